// Round 2
// baseline (378.530 us; speedup 1.0000x reference)
//
#include <hip/hip_runtime.h>
#include <hip/hip_bf16.h>

// ---------------- helpers ----------------
typedef __attribute__((ext_vector_type(8))) short bf16x8;
typedef __attribute__((ext_vector_type(4))) float f32x4;
typedef __attribute__((ext_vector_type(2))) float f32x2;

__device__ __forceinline__ unsigned short f2bf(float f) {
    __hip_bfloat16 h = __float2bfloat16(f);   // round-to-nearest-even
    return __builtin_bit_cast(unsigned short, h);
}
// unpack packed bf16 pair -> f32x2 {lo, hi}
__device__ __forceinline__ f32x2 up2(unsigned int u) {
    f32x2 r;
    r.x = __builtin_bit_cast(float, u << 16);
    r.y = __builtin_bit_cast(float, u & 0xffff0000u);
    return r;
}
__device__ __forceinline__ unsigned int packbf(float lo, float hi) {
    return (unsigned int)f2bf(lo) | ((unsigned int)f2bf(hi) << 16);
}

// ---------------- CSR build ----------------
__global__ void k_hist(const int* __restrict__ dst, int* __restrict__ counts,
                       int* __restrict__ rank, int E) {
    int e = blockIdx.x * blockDim.x + threadIdx.x;
    if (e < E) rank[e] = atomicAdd(&counts[dst[e]], 1);
}

__global__ void k_psum(const int* __restrict__ counts, int* __restrict__ part, int NN) {
    __shared__ int s[256];
    int t = threadIdx.x;
    int i = blockIdx.x * 256 + t;
    s[t] = (i < NN) ? counts[i] : 0;
    __syncthreads();
    for (int off = 128; off > 0; off >>= 1) {
        if (t < off) s[t] += s[t + off];
        __syncthreads();
    }
    if (t == 0) part[blockIdx.x] = s[0];
}

__global__ void k_scatter_rs(const int* __restrict__ counts, const int* __restrict__ part,
                             int* __restrict__ row_start, int NN, int E) {
    __shared__ int s[256];
    __shared__ int q[256];
    int t = threadIdx.x;
    int b = blockIdx.x;
    q[t] = (t < b) ? part[t] : 0;
    __syncthreads();
    for (int off = 128; off > 0; off >>= 1) {
        if (t < off) q[t] += q[t + off];
        __syncthreads();
    }
    int boff = q[0];
    __syncthreads();
    int i = b * 256 + t;
    int v = (i < NN) ? counts[i] : 0;
    s[t] = v; __syncthreads();
    for (int off = 1; off < 256; off <<= 1) {
        int u = (t >= off) ? s[t - off] : 0;
        __syncthreads();
        s[t] += u;
        __syncthreads();
    }
    int ex = s[t] - v + boff;
    if (i < NN) row_start[i] = ex;
    if (i == NN - 1) row_start[NN] = E;
}

__global__ void k_fill(const int* __restrict__ src, const int* __restrict__ dst,
                       const int* __restrict__ rank, const int* __restrict__ row_start,
                       unsigned short* __restrict__ csrc, int E) {
    int e = blockIdx.x * blockDim.x + threadIdx.x;
    if (e < E) csrc[row_start[dst[e]] + rank[e]] = (unsigned short)src[e];
}

// ---------------- fused dtype conversions (one launch) ----------------
__global__ void k_cvt_all(const float4* __restrict__ x4, ushort4* __restrict__ xb4, int n4x, int nbx,
                          const float* __restrict__ W1, unsigned short* __restrict__ w1t,
                          const float* __restrict__ W2, unsigned short* __restrict__ w2t,
                          const float* __restrict__ W3, unsigned short* __restrict__ w3t) {
    int b = blockIdx.x;
    if (b < nbx) {
        int i = b * 256 + threadIdx.x;
        if (i < n4x) {
            float4 v = x4[i];
            ushort4 o; o.x = f2bf(v.x); o.y = f2bf(v.y); o.z = f2bf(v.z); o.w = f2bf(v.w);
            xb4[i] = o;
        }
        return;
    }
    b -= nbx;
    const float* w; unsigned short* wt; int K;
    if (b < 128)      { w = W1; wt = w1t; K = 128; }
    else if (b < 384) { w = W2; wt = w2t; K = 256; b -= 128; }
    else              { w = W3; wt = w3t; K = 256; b -= 384; }
    int i = b * 256 + threadIdx.x;   // i < K*256
    int k = i >> 8, n = i & 255;
    wt[n * K + k] = f2bf(w[i]);
}

// ---------------- bf16 CSR aggregation (layer 1, x table, F=128) ----------------
// Tail-free masked-batch gather: was latency-bound (VALU 45%, HBM 33%, occ
// 40%, nothing saturated). Mean degree 16 meant the old 8-edge batch ran
// once then fell into a serialized j+=2 tail. Now: always full batches of
// 16 edges (8 gathered rows in flight per lane); out-of-range edges are
// neutralized by zeroing the loaded value. No divergent tail path.
__global__ __launch_bounds__(256)
void k_agg(const unsigned short* __restrict__ h, const int* __restrict__ rs,
           const unsigned short* __restrict__ csrc, unsigned short* __restrict__ out, int NN) {
    int gid = blockIdx.x * blockDim.x + threadIdx.x;
    int node = gid >> 6;
    if (node >= NN) return;
    int lane = threadIdx.x & 63;
    int half = lane >> 5, l32 = lane & 31;
    int k0 = rs[node], k1 = rs[node + 1];
    int cnt = k1 - k0;

    f32x2 acc[4][2];
#pragma unroll
    for (int b = 0; b < 4; ++b)
#pragma unroll
        for (int i = 0; i < 2; ++i) acc[b][i] = (f32x2){0.f, 0.f};

    for (int base = 0; base < cnt; base += 64) {
        int nk = min(cnt - base, 64);
        int myidx = (lane < nk) ? (int)csrc[k0 + base + lane] : 0;
        for (int j = 0; j < nk; j += 16) {
            int s[8]; uint2 v[8];
#pragma unroll
            for (int b = 0; b < 8; ++b) {
                int jj = j + 2 * b + half;
                s[b] = __shfl(myidx, jj & 63, 64);
            }
#pragma unroll
            for (int b = 0; b < 8; ++b) {
                uint2 t = ((const uint2*)(h + (size_t)s[b] * 128))[l32];
                bool valid = (j + 2 * b + half) < nk;
                v[b].x = valid ? t.x : 0u;
                v[b].y = valid ? t.y : 0u;
            }
#pragma unroll
            for (int b = 0; b < 8; ++b) {
                acc[b & 3][0] += up2(v[b].x);
                acc[b & 3][1] += up2(v[b].y);
            }
        }
    }

#pragma unroll
    for (int i = 0; i < 2; ++i) {
        acc[0][i] += acc[1][i];
        acc[2][i] += acc[3][i];
        acc[0][i] += acc[2][i];
    }
#pragma unroll
    for (int i = 0; i < 2; ++i) {
        acc[0][i].x += __shfl(acc[0][i].x, l32 + 32, 64);
        acc[0][i].y += __shfl(acc[0][i].y, l32 + 32, 64);
    }
    if (half == 0) {
        uint2 o;
        o.x = packbf(acc[0][0].x, acc[0][0].y); o.y = packbf(acc[0][1].x, acc[0][1].y);
        ((uint2*)(out + (size_t)node * 128))[l32] = o;
    }
}

// ---------------- int8 CSR aggregation (layers 2&3) ----------------
// Same tail-free masked-batch structure; invalid edges contribute 0 via a
// zeroed scale (the gather itself uses a clamped-valid index, so it is
// always a legal address).
__global__ __launch_bounds__(256)
void k_agg8(const unsigned char* __restrict__ h8, const float* __restrict__ scales,
            const int* __restrict__ rs, const unsigned short* __restrict__ csrc,
            unsigned short* __restrict__ out, int NN) {
    int gid = blockIdx.x * blockDim.x + threadIdx.x;
    int node = gid >> 6;
    if (node >= NN) return;
    int lane = threadIdx.x & 63;
    int half = lane >> 5, l32 = lane & 31;
    int qoff = l32 >> 3;               // 64-col quarter of this lane's 8 feats
    int k0 = rs[node], k1 = rs[node + 1];
    int cnt = k1 - k0;

    f32x2 acc[4][4];
#pragma unroll
    for (int b = 0; b < 4; ++b)
#pragma unroll
        for (int i = 0; i < 4; ++i) acc[b][i] = (f32x2){0.f, 0.f};

    auto accum = [&](int b, uint2 v, float sc) {
        unsigned x = v.x, y = v.y;
        acc[b][0].x += (float)(x & 0xff) * sc;
        acc[b][0].y += (float)((x >> 8) & 0xff) * sc;
        acc[b][1].x += (float)((x >> 16) & 0xff) * sc;
        acc[b][1].y += (float)(x >> 24) * sc;
        acc[b][2].x += (float)(y & 0xff) * sc;
        acc[b][2].y += (float)((y >> 8) & 0xff) * sc;
        acc[b][3].x += (float)((y >> 16) & 0xff) * sc;
        acc[b][3].y += (float)(y >> 24) * sc;
    };

    for (int base = 0; base < cnt; base += 64) {
        int nk = min(cnt - base, 64);
        int myidx = (lane < nk) ? (int)csrc[k0 + base + lane] : 0;
        for (int j = 0; j < nk; j += 16) {
            int s[8]; uint2 v[8]; float sc[8];
#pragma unroll
            for (int b = 0; b < 8; ++b) {
                int jj = j + 2 * b + half;
                s[b] = __shfl(myidx, jj & 63, 64);
            }
#pragma unroll
            for (int b = 0; b < 8; ++b) {
                v[b] = ((const uint2*)(h8 + (size_t)s[b] * 256))[l32];
                float t = scales[s[b] * 4 + qoff];
                sc[b] = ((j + 2 * b + half) < nk) ? t : 0.f;
            }
#pragma unroll
            for (int b = 0; b < 8; ++b) accum(b & 3, v[b], sc[b]);
        }
    }

#pragma unroll
    for (int i = 0; i < 4; ++i) {
        acc[0][i] += acc[1][i];
        acc[2][i] += acc[3][i];
        acc[0][i] += acc[2][i];
    }
#pragma unroll
    for (int i = 0; i < 4; ++i) {
        acc[0][i].x += __shfl(acc[0][i].x, l32 + 32, 64);
        acc[0][i].y += __shfl(acc[0][i].y, l32 + 32, 64);
    }
    if (half == 0) {
        uint4 o;
        o.x = packbf(acc[0][0].x, acc[0][0].y); o.y = packbf(acc[0][1].x, acc[0][1].y);
        o.z = packbf(acc[0][2].x, acc[0][2].y); o.w = packbf(acc[0][3].x, acc[0][3].y);
        ((uint4*)(out + (size_t)node * 256))[l32] = o;
    }
}

// ---------------- MFMA GEMM: C = relu(A @ W + b) ----------------
// Stage-B-once design. Round-0 kernel was barrier-latency-bound (2 barriers
// per K-step); round-1 LDS-free kernel was L2-BW-bound (B frags re-read
// from L2 every K-step: ~1.6 GB per K=256 GEMM). Since K <= 256, a block's
// entire 64-col B-slab is only 16-32 KB: stage it in LDS ONCE, one
// __syncthreads, then a fully-unrolled barrier-free K-loop with A direct
// from global (line-perfect: 16 rows x 64 B per fragment load) and B from
// LDS (padded stride K+8 -> 2-way bank alias = free).
// Block = 4 waves; block covers 256 rows x 64 cols; wave w owns rows
// w*64..w*64+63. Grid = (4 col-slabs, ceil(M/256)); col-siblings adjacent
// in dispatch order for A L2 reuse.
template <bool QUANT, int K>
__global__ __launch_bounds__(256, 4)
void k_gemm(const unsigned short* __restrict__ A, const unsigned short* __restrict__ Bt,
            const float* __restrict__ bias, void* __restrict__ Cout,
            float* __restrict__ scales, int M) {
    constexpr int LDB = K + 8;
    __shared__ unsigned short Bs[64 * LDB];
    int tid = threadIdx.x;
    int lane = tid & 63, quad = lane >> 4, l16 = lane & 15;
    int w = tid >> 6;
    int cbase = blockIdx.x * 64;
    int mrow0 = blockIdx.y * 256 + w * 64;

    // stage the block's B slab (64 cols x K) once
    constexpr int CH = K / 8;            // uint4 chunks per slab row
    constexpr int NCH = 64 * CH;
#pragma unroll
    for (int ch = tid; ch < NCH; ch += 256) {
        int c = ch / CH;
        int kk = (ch % CH) * 8;
        uint4 v = *((const uint4*)(Bt + (size_t)(cbase + c) * K + kk));
        *((uint4*)&Bs[c * LDB + kk]) = v;
    }
    __syncthreads();

    // A fragment base pointers (rows clamped; tail rows never stored)
    const unsigned short* Ap[4];
#pragma unroll
    for (int mt = 0; mt < 4; ++mt) {
        int r = mrow0 + mt * 16 + l16;
        if (r >= M) r = M - 1;
        Ap[mt] = A + (size_t)r * K + quad * 8;
    }

    f32x4 acc[4][4];
#pragma unroll
    for (int i = 0; i < 4; ++i)
#pragma unroll
        for (int j = 0; j < 4; ++j) acc[i][j] = (f32x4){0.f, 0.f, 0.f, 0.f};

#pragma unroll
    for (int s = 0; s < K / 32; ++s) {
        bf16x8 af[4], bfr[4];
#pragma unroll
        for (int mt = 0; mt < 4; ++mt) af[mt] = *((const bf16x8*)(Ap[mt] + s * 32));
#pragma unroll
        for (int nt = 0; nt < 4; ++nt)
            bfr[nt] = *((const bf16x8*)&Bs[(nt * 16 + l16) * LDB + s * 32 + quad * 8]);
#pragma unroll
        for (int mt = 0; mt < 4; ++mt)
#pragma unroll
            for (int nt = 0; nt < 4; ++nt)
                acc[mt][nt] = __builtin_amdgcn_mfma_f32_16x16x32_bf16(af[mt], bfr[nt], acc[mt][nt], 0, 0, 0);
    }

    // bias + relu in-place.  C/D layout: col = lane&15, row = quad*4 + reg
    float bv[4];
#pragma unroll
    for (int nt = 0; nt < 4; ++nt) bv[nt] = bias[cbase + nt * 16 + l16];
#pragma unroll
    for (int mt = 0; mt < 4; ++mt)
#pragma unroll
        for (int nt = 0; nt < 4; ++nt)
#pragma unroll
            for (int r = 0; r < 4; ++r) {
                float v = acc[mt][nt][r] + bv[nt];
                acc[mt][nt][r] = v > 0.f ? v : 0.f;
            }

    if constexpr (QUANT) {
        unsigned char* h8 = (unsigned char*)Cout;
        int qid = blockIdx.x;            // 64-col quarter id
#pragma unroll
        for (int mt = 0; mt < 4; ++mt) {
#pragma unroll
            for (int r = 0; r < 4; ++r) {
                float mx = fmaxf(fmaxf(acc[mt][0][r], acc[mt][1][r]),
                                 fmaxf(acc[mt][2][r], acc[mt][3][r]));
#pragma unroll
                for (int off = 1; off < 16; off <<= 1)
                    mx = fmaxf(mx, __shfl_xor(mx, off, 64));
                float inv = mx > 0.f ? 255.0f / mx : 0.0f;
                int m = mrow0 + mt * 16 + quad * 4 + r;
                if (m < M) {
#pragma unroll
                    for (int nt = 0; nt < 4; ++nt) {
                        int n = cbase + nt * 16 + l16;
                        unsigned u = (unsigned)(acc[mt][nt][r] * inv + 0.5f);
                        h8[(size_t)m * 256 + n] = (unsigned char)u;
                    }
                    if (l16 == 0) scales[(size_t)m * 4 + qid] = mx * (1.0f / 255.0f);
                }
            }
        }
    } else {
        float* C = (float*)Cout;
#pragma unroll
        for (int mt = 0; mt < 4; ++mt)
#pragma unroll
            for (int nt = 0; nt < 4; ++nt) {
                int n = cbase + nt * 16 + l16;
#pragma unroll
                for (int r = 0; r < 4; ++r) {
                    int m = mrow0 + mt * 16 + quad * 4 + r;
                    if (m < M) C[(size_t)m * 256 + n] = acc[mt][nt][r];
                }
            }
    }
}

// ---------------- host ----------------
static inline size_t alignup(size_t x) { return (x + 255) & ~(size_t)255; }

extern "C" void kernel_launch(void* const* d_in, const int* in_sizes, int n_in,
                              void* d_out, int out_size, void* d_ws, size_t ws_size,
                              hipStream_t stream) {
    const float* x  = (const float*)d_in[0];
    const int* ei   = (const int*)d_in[1];    // int32 on device (harness converts)
    const float* W1 = (const float*)d_in[2];
    const float* b1 = (const float*)d_in[3];
    const float* W2 = (const float*)d_in[4];
    const float* b2 = (const float*)d_in[5];
    const float* W3 = (const float*)d_in[6];
    const float* b3 = (const float*)d_in[7];

    const int M = in_sizes[0] / 128;      // 50000 nodes
    const int E = in_sizes[1] / 2;        // 800000 edges
    const int* srcp = ei;
    const int* dstp = ei + E;
    const int nscan = (M + 255) / 256;

    // workspace carve-up (~45 MB). h8 (12.8 MB) + scales (0.8 MB) live in
    // d_out: both dead before gemm3 overwrites d_out with fp32.
    char* p = (char*)d_ws;
    size_t off = 0;
    auto carve = [&](size_t bytes) { void* r = p + off; off += alignup(bytes); return r; };
    int* counts    = (int*)carve((size_t)M * 4);
    int* row_start = (int*)carve((size_t)(M + 1) * 4);
    int* part      = (int*)carve((size_t)256 * 4);
    int* rank      = (int*)carve((size_t)E * 4);
    unsigned short* csrc = (unsigned short*)carve((size_t)E * 2);
    unsigned short* w1t = (unsigned short*)carve((size_t)128 * 256 * 2);
    unsigned short* w2t = (unsigned short*)carve((size_t)256 * 256 * 2);
    unsigned short* w3t = (unsigned short*)carve((size_t)256 * 256 * 2);
    unsigned short* xb  = (unsigned short*)carve((size_t)M * 128 * 2);
    unsigned short* ab  = (unsigned short*)carve((size_t)M * 256 * 2);  // a1/a2/a3 (bf16)
    unsigned char* h8   = (unsigned char*)d_out;                         // h1/h2 int8
    float* scales       = (float*)((char*)d_out + (size_t)M * 256);      // 4 per node

    // 1) CSR build (rank trick: no atomics in fill)
    hipMemsetAsync(counts, 0, (size_t)M * 4, stream);
    k_hist<<<(E + 255) / 256, 256, 0, stream>>>(dstp, counts, rank, E);
    k_psum<<<nscan, 256, 0, stream>>>(counts, part, M);
    k_scatter_rs<<<nscan, 256, 0, stream>>>(counts, part, row_start, M, E);
    k_fill<<<(E + 255) / 256, 256, 0, stream>>>(srcp, dstp, rank, row_start, csrc, E);

    // 2) conversions (single launch)
    int n4x = M * 128 / 4;
    int nbx = (n4x + 255) / 256;
    k_cvt_all<<<nbx + 128 + 256 + 256, 256, 0, stream>>>(
        (const float4*)x, (ushort4*)xb, n4x, nbx, W1, w1t, W2, w2t, W3, w3t);

    dim3 ggrid(4, (M + 255) / 256);
    int aggblocks = (M * 64 + 255) / 256;

    // layer 1: a1 = agg(x); h1 = quant8(relu(a1 @ W1 + b1))
    k_agg<<<aggblocks, 256, 0, stream>>>(xb, row_start, csrc, ab, M);
    k_gemm<true, 128><<<ggrid, 256, 0, stream>>>(ab, w1t, b1, h8, scales, M);

    // layer 2: a2 = agg8(h1); h2 = quant8(relu(a2 @ W2 + b2))
    k_agg8<<<aggblocks, 256, 0, stream>>>(h8, scales, row_start, csrc, ab, M);
    k_gemm<true, 256><<<ggrid, 256, 0, stream>>>(ab, w2t, b2, h8, scales, M);

    // layer 3: a3 = agg8(h2); out = relu(a3 @ W3 + b3)
    k_agg8<<<aggblocks, 256, 0, stream>>>(h8, scales, row_start, csrc, ab, M);
    k_gemm<false, 256><<<ggrid, 256, 0, stream>>>(ab, w3t, b3, d_out, nullptr, M);
}

// Round 4
// 344.320 us; speedup vs baseline: 1.0994x; 1.0994x over previous
//
#include <hip/hip_runtime.h>
#include <hip/hip_bf16.h>

// ---------------- helpers ----------------
typedef __attribute__((ext_vector_type(8))) short bf16x8;
typedef __attribute__((ext_vector_type(4))) float f32x4;
typedef __attribute__((ext_vector_type(2))) float f32x2;

__device__ __forceinline__ unsigned short f2bf(float f) {
    __hip_bfloat16 h = __float2bfloat16(f);   // round-to-nearest-even
    return __builtin_bit_cast(unsigned short, h);
}
// unpack packed bf16 pair -> f32x2 {lo, hi}
__device__ __forceinline__ f32x2 up2(unsigned int u) {
    f32x2 r;
    r.x = __builtin_bit_cast(float, u << 16);
    r.y = __builtin_bit_cast(float, u & 0xffff0000u);
    return r;
}
__device__ __forceinline__ unsigned int packbf(float lo, float hi) {
    return (unsigned int)f2bf(lo) | ((unsigned int)f2bf(hi) << 16);
}

// ---------------- CSR build ----------------
__global__ void k_hist(const int* __restrict__ dst, int* __restrict__ counts,
                       int* __restrict__ rank, int E) {
    int e = blockIdx.x * blockDim.x + threadIdx.x;
    if (e < E) rank[e] = atomicAdd(&counts[dst[e]], 1);
}

__global__ void k_psum(const int* __restrict__ counts, int* __restrict__ part, int NN) {
    __shared__ int s[256];
    int t = threadIdx.x;
    int i = blockIdx.x * 256 + t;
    s[t] = (i < NN) ? counts[i] : 0;
    __syncthreads();
    for (int off = 128; off > 0; off >>= 1) {
        if (t < off) s[t] += s[t + off];
        __syncthreads();
    }
    if (t == 0) part[blockIdx.x] = s[0];
}

__global__ void k_scatter_rs(const int* __restrict__ counts, const int* __restrict__ part,
                             int* __restrict__ row_start, int NN, int E) {
    __shared__ int s[256];
    __shared__ int q[256];
    int t = threadIdx.x;
    int b = blockIdx.x;
    q[t] = (t < b) ? part[t] : 0;
    __syncthreads();
    for (int off = 128; off > 0; off >>= 1) {
        if (t < off) q[t] += q[t + off];
        __syncthreads();
    }
    int boff = q[0];
    __syncthreads();
    int i = b * 256 + t;
    int v = (i < NN) ? counts[i] : 0;
    s[t] = v; __syncthreads();
    for (int off = 1; off < 256; off <<= 1) {
        int u = (t >= off) ? s[t - off] : 0;
        __syncthreads();
        s[t] += u;
        __syncthreads();
    }
    int ex = s[t] - v + boff;
    if (i < NN) row_start[i] = ex;
    if (i == NN - 1) row_start[NN] = E;
}

__global__ void k_fill(const int* __restrict__ src, const int* __restrict__ dst,
                       const int* __restrict__ rank, const int* __restrict__ row_start,
                       unsigned short* __restrict__ csrc, int E) {
    int e = blockIdx.x * blockDim.x + threadIdx.x;
    if (e < E) csrc[row_start[dst[e]] + rank[e]] = (unsigned short)src[e];
}

// ---------------- fused dtype conversions (one launch) ----------------
__global__ void k_cvt_all(const float4* __restrict__ x4, ushort4* __restrict__ xb4, int n4x, int nbx,
                          const float* __restrict__ W1, unsigned short* __restrict__ w1t,
                          const float* __restrict__ W2, unsigned short* __restrict__ w2t,
                          const float* __restrict__ W3, unsigned short* __restrict__ w3t) {
    int b = blockIdx.x;
    if (b < nbx) {
        int i = b * 256 + threadIdx.x;
        if (i < n4x) {
            float4 v = x4[i];
            ushort4 o; o.x = f2bf(v.x); o.y = f2bf(v.y); o.z = f2bf(v.z); o.w = f2bf(v.w);
            xb4[i] = o;
        }
        return;
    }
    b -= nbx;
    const float* w; unsigned short* wt; int K;
    if (b < 128)      { w = W1; wt = w1t; K = 128; }
    else if (b < 384) { w = W2; wt = w2t; K = 256; b -= 128; }
    else              { w = W3; wt = w3t; K = 256; b -= 384; }
    int i = b * 256 + threadIdx.x;   // i < K*256
    int k = i >> 8, n = i & 255;
    wt[n * K + k] = f2bf(w[i]);
}

// ---------------- bf16 CSR aggregation (layer 1, x table, F=128) ----------------
// Round-2 post-mortem: 16-edge masked batches issued ~35% more gathers
// (degrees 17..32 round up) and VGPR 68 -> occupancy 25%. Round-1's real
// defect was only the serialized 2-at-a-time tail. This version: 4-deep
// gathers at 8-edge granularity (same issue count as round-1), mask only
// the last batch, and ping-pong two buffers so batch b+1's loads are in
// flight while batch b is consumed (nk is wave-uniform -> uniform branch).
__global__ __launch_bounds__(256)
void k_agg(const unsigned short* __restrict__ h, const int* __restrict__ rs,
           const unsigned short* __restrict__ csrc, unsigned short* __restrict__ out, int NN) {
    int gid = blockIdx.x * blockDim.x + threadIdx.x;
    int node = gid >> 6;
    if (node >= NN) return;
    int lane = threadIdx.x & 63;
    int half = lane >> 5, l32 = lane & 31;
    int k0 = rs[node], k1 = rs[node + 1];
    int cnt = k1 - k0;

    f32x2 acc[2][2];
#pragma unroll
    for (int c = 0; c < 2; ++c)
#pragma unroll
        for (int i = 0; i < 2; ++i) acc[c][i] = (f32x2){0.f, 0.f};

    for (int base = 0; base < cnt; base += 64) {
        int nk = min(cnt - base, 64);
        int myidx = (lane < nk) ? (int)csrc[k0 + base + lane] : 0;
        int nb = (nk + 7) >> 3;

        auto issue = [&](int j, uint2 (&v)[4]) {
#pragma unroll
            for (int b = 0; b < 4; ++b) {
                int s = __shfl(myidx, (j + 2 * b + half) & 63, 64);
                v[b] = ((const uint2*)(h + (size_t)s * 128))[l32];
            }
        };
        auto consume = [&](int j, uint2 (&v)[4]) {
#pragma unroll
            for (int b = 0; b < 4; ++b) {
                bool valid = (j + 2 * b + half) < nk;
                unsigned vx = valid ? v[b].x : 0u;
                unsigned vy = valid ? v[b].y : 0u;
                acc[b & 1][0] += up2(vx);
                acc[b & 1][1] += up2(vy);
            }
        };

        uint2 vA[4], vB[4];
        issue(0, vA);
        for (int b = 1; b < nb; ++b) {
            if (b & 1) { issue(b * 8, vB); consume((b - 1) * 8, vA); }
            else       { issue(b * 8, vA); consume((b - 1) * 8, vB); }
        }
        if (nb & 1) consume((nb - 1) * 8, vA);
        else        consume((nb - 1) * 8, vB);
    }

#pragma unroll
    for (int i = 0; i < 2; ++i) acc[0][i] += acc[1][i];
#pragma unroll
    for (int i = 0; i < 2; ++i) {
        acc[0][i].x += __shfl(acc[0][i].x, l32 + 32, 64);
        acc[0][i].y += __shfl(acc[0][i].y, l32 + 32, 64);
    }
    if (half == 0) {
        uint2 o;
        o.x = packbf(acc[0][0].x, acc[0][0].y); o.y = packbf(acc[0][1].x, acc[0][1].y);
        ((uint2*)(out + (size_t)node * 128))[l32] = o;
    }
}

// ---------------- int8 CSR aggregation (layers 2&3) ----------------
// Same ping-pong structure. Masking zeroes the SCALE (gather address is
// always legal: wrapped shfl indices read real node ids). Accumulate as
// f32x2 packed math: v_cvt_f32_ubyte0-3 + v_pk_fma_f32 (~1.5 VALU/feature
// vs ~3 scalar). 2 accumulator chains keep VGPR near round-1's budget.
__global__ __launch_bounds__(256)
void k_agg8(const unsigned char* __restrict__ h8, const float* __restrict__ scales,
            const int* __restrict__ rs, const unsigned short* __restrict__ csrc,
            unsigned short* __restrict__ out, int NN) {
    int gid = blockIdx.x * blockDim.x + threadIdx.x;
    int node = gid >> 6;
    if (node >= NN) return;
    int lane = threadIdx.x & 63;
    int half = lane >> 5, l32 = lane & 31;
    int qoff = l32 >> 3;               // 64-col quarter of this lane's 8 feats
    int k0 = rs[node], k1 = rs[node + 1];
    int cnt = k1 - k0;

    f32x2 acc[2][4];
#pragma unroll
    for (int c = 0; c < 2; ++c)
#pragma unroll
        for (int i = 0; i < 4; ++i) acc[c][i] = (f32x2){0.f, 0.f};

    for (int base = 0; base < cnt; base += 64) {
        int nk = min(cnt - base, 64);
        int myidx = (lane < nk) ? (int)csrc[k0 + base + lane] : 0;
        int nb = (nk + 7) >> 3;

        auto issue = [&](int j, uint2 (&v)[4], float (&c)[4]) {
#pragma unroll
            for (int b = 0; b < 4; ++b) {
                int s = __shfl(myidx, (j + 2 * b + half) & 63, 64);
                v[b] = ((const uint2*)(h8 + (size_t)s * 256))[l32];
                c[b] = scales[s * 4 + qoff];
            }
        };
        auto consume = [&](int j, uint2 (&v)[4], float (&c)[4]) {
#pragma unroll
            for (int b = 0; b < 4; ++b) {
                float sc = ((j + 2 * b + half) < nk) ? c[b] : 0.f;
                f32x2 s2 = {sc, sc};
                unsigned x = v[b].x, y = v[b].y;
                int ch = b & 1;
                acc[ch][0] += (f32x2){(float)(x & 0xff), (float)((x >> 8) & 0xff)} * s2;
                acc[ch][1] += (f32x2){(float)((x >> 16) & 0xff), (float)(x >> 24)} * s2;
                acc[ch][2] += (f32x2){(float)(y & 0xff), (float)((y >> 8) & 0xff)} * s2;
                acc[ch][3] += (f32x2){(float)((y >> 16) & 0xff), (float)(y >> 24)} * s2;
            }
        };

        uint2 vA[4], vB[4]; float cA[4], cB[4];
        issue(0, vA, cA);
        for (int b = 1; b < nb; ++b) {
            if (b & 1) { issue(b * 8, vB, cB); consume((b - 1) * 8, vA, cA); }
            else       { issue(b * 8, vA, cA); consume((b - 1) * 8, vB, cB); }
        }
        if (nb & 1) consume((nb - 1) * 8, vA, cA);
        else        consume((nb - 1) * 8, vB, cB);
    }

#pragma unroll
    for (int i = 0; i < 4; ++i) acc[0][i] += acc[1][i];
#pragma unroll
    for (int i = 0; i < 4; ++i) {
        acc[0][i].x += __shfl(acc[0][i].x, l32 + 32, 64);
        acc[0][i].y += __shfl(acc[0][i].y, l32 + 32, 64);
    }
    if (half == 0) {
        uint4 o;
        o.x = packbf(acc[0][0].x, acc[0][0].y); o.y = packbf(acc[0][1].x, acc[0][1].y);
        o.z = packbf(acc[0][2].x, acc[0][2].y); o.w = packbf(acc[0][3].x, acc[0][3].y);
        ((uint4*)(out + (size_t)node * 256))[l32] = o;
    }
}

// ---------------- MFMA GEMM: C = relu(A @ W + b) ----------------
// Stage-B-once design (round 2, unchanged; still unmeasured in isolation).
// K <= 256 so a block's 64-col B-slab (16-32 KB) is staged in LDS ONCE,
// one __syncthreads, then a fully-unrolled barrier-free K-loop with A
// direct from global (line-perfect: 16 rows x 64 B per fragment load) and
// B from LDS (padded stride K+8 -> 2-way bank alias = free).
template <bool QUANT, int K>
__global__ __launch_bounds__(256, 4)
void k_gemm(const unsigned short* __restrict__ A, const unsigned short* __restrict__ Bt,
            const float* __restrict__ bias, void* __restrict__ Cout,
            float* __restrict__ scales, int M) {
    constexpr int LDB = K + 8;
    __shared__ unsigned short Bs[64 * LDB];
    int tid = threadIdx.x;
    int lane = tid & 63, quad = lane >> 4, l16 = lane & 15;
    int w = tid >> 6;
    int cbase = blockIdx.x * 64;
    int mrow0 = blockIdx.y * 256 + w * 64;

    // stage the block's B slab (64 cols x K) once
    constexpr int CH = K / 8;            // uint4 chunks per slab row
    constexpr int NCH = 64 * CH;
#pragma unroll
    for (int ch = tid; ch < NCH; ch += 256) {
        int c = ch / CH;
        int kk = (ch % CH) * 8;
        uint4 v = *((const uint4*)(Bt + (size_t)(cbase + c) * K + kk));
        *((uint4*)&Bs[c * LDB + kk]) = v;
    }
    __syncthreads();

    // A fragment base pointers (rows clamped; tail rows never stored)
    const unsigned short* Ap[4];
#pragma unroll
    for (int mt = 0; mt < 4; ++mt) {
        int r = mrow0 + mt * 16 + l16;
        if (r >= M) r = M - 1;
        Ap[mt] = A + (size_t)r * K + quad * 8;
    }

    f32x4 acc[4][4];
#pragma unroll
    for (int i = 0; i < 4; ++i)
#pragma unroll
        for (int j = 0; j < 4; ++j) acc[i][j] = (f32x4){0.f, 0.f, 0.f, 0.f};

#pragma unroll
    for (int s = 0; s < K / 32; ++s) {
        bf16x8 af[4], bfr[4];
#pragma unroll
        for (int mt = 0; mt < 4; ++mt) af[mt] = *((const bf16x8*)(Ap[mt] + s * 32));
#pragma unroll
        for (int nt = 0; nt < 4; ++nt)
            bfr[nt] = *((const bf16x8*)&Bs[(nt * 16 + l16) * LDB + s * 32 + quad * 8]);
#pragma unroll
        for (int mt = 0; mt < 4; ++mt)
#pragma unroll
            for (int nt = 0; nt < 4; ++nt)
                acc[mt][nt] = __builtin_amdgcn_mfma_f32_16x16x32_bf16(af[mt], bfr[nt], acc[mt][nt], 0, 0, 0);
    }

    // bias + relu in-place.  C/D layout: col = lane&15, row = quad*4 + reg
    float bv[4];
#pragma unroll
    for (int nt = 0; nt < 4; ++nt) bv[nt] = bias[cbase + nt * 16 + l16];
#pragma unroll
    for (int mt = 0; mt < 4; ++mt)
#pragma unroll
        for (int nt = 0; nt < 4; ++nt)
#pragma unroll
            for (int r = 0; r < 4; ++r) {
                float v = acc[mt][nt][r] + bv[nt];
                acc[mt][nt][r] = v > 0.f ? v : 0.f;
            }

    if constexpr (QUANT) {
        unsigned char* h8 = (unsigned char*)Cout;
        int qid = blockIdx.x;            // 64-col quarter id
#pragma unroll
        for (int mt = 0; mt < 4; ++mt) {
#pragma unroll
            for (int r = 0; r < 4; ++r) {
                float mx = fmaxf(fmaxf(acc[mt][0][r], acc[mt][1][r]),
                                 fmaxf(acc[mt][2][r], acc[mt][3][r]));
#pragma unroll
                for (int off = 1; off < 16; off <<= 1)
                    mx = fmaxf(mx, __shfl_xor(mx, off, 64));
                float inv = mx > 0.f ? 255.0f / mx : 0.0f;
                int m = mrow0 + mt * 16 + quad * 4 + r;
                if (m < M) {
#pragma unroll
                    for (int nt = 0; nt < 4; ++nt) {
                        int n = cbase + nt * 16 + l16;
                        unsigned u = (unsigned)(acc[mt][nt][r] * inv + 0.5f);
                        h8[(size_t)m * 256 + n] = (unsigned char)u;
                    }
                    if (l16 == 0) scales[(size_t)m * 4 + qid] = mx * (1.0f / 255.0f);
                }
            }
        }
    } else {
        float* C = (float*)Cout;
#pragma unroll
        for (int mt = 0; mt < 4; ++mt)
#pragma unroll
            for (int nt = 0; nt < 4; ++nt) {
                int n = cbase + nt * 16 + l16;
#pragma unroll
                for (int r = 0; r < 4; ++r) {
                    int m = mrow0 + mt * 16 + quad * 4 + r;
                    if (m < M) C[(size_t)m * 256 + n] = acc[mt][nt][r];
                }
            }
    }
}

// ---------------- host ----------------
static inline size_t alignup(size_t x) { return (x + 255) & ~(size_t)255; }

extern "C" void kernel_launch(void* const* d_in, const int* in_sizes, int n_in,
                              void* d_out, int out_size, void* d_ws, size_t ws_size,
                              hipStream_t stream) {
    const float* x  = (const float*)d_in[0];
    const int* ei   = (const int*)d_in[1];    // int32 on device (harness converts)
    const float* W1 = (const float*)d_in[2];
    const float* b1 = (const float*)d_in[3];
    const float* W2 = (const float*)d_in[4];
    const float* b2 = (const float*)d_in[5];
    const float* W3 = (const float*)d_in[6];
    const float* b3 = (const float*)d_in[7];

    const int M = in_sizes[0] / 128;      // 50000 nodes
    const int E = in_sizes[1] / 2;        // 800000 edges
    const int* srcp = ei;
    const int* dstp = ei + E;
    const int nscan = (M + 255) / 256;

    // workspace carve-up (~45 MB). h8 (12.8 MB) + scales (0.8 MB) live in
    // d_out: both dead before gemm3 overwrites d_out with fp32.
    char* p = (char*)d_ws;
    size_t off = 0;
    auto carve = [&](size_t bytes) { void* r = p + off; off += alignup(bytes); return r; };
    int* counts    = (int*)carve((size_t)M * 4);
    int* row_start = (int*)carve((size_t)(M + 1) * 4);
    int* part      = (int*)carve((size_t)256 * 4);
    int* rank      = (int*)carve((size_t)E * 4);
    unsigned short* csrc = (unsigned short*)carve((size_t)E * 2);
    unsigned short* w1t = (unsigned short*)carve((size_t)128 * 256 * 2);
    unsigned short* w2t = (unsigned short*)carve((size_t)256 * 256 * 2);
    unsigned short* w3t = (unsigned short*)carve((size_t)256 * 256 * 2);
    unsigned short* xb  = (unsigned short*)carve((size_t)M * 128 * 2);
    unsigned short* ab  = (unsigned short*)carve((size_t)M * 256 * 2);  // a1/a2/a3 (bf16)
    unsigned char* h8   = (unsigned char*)d_out;                         // h1/h2 int8
    float* scales       = (float*)((char*)d_out + (size_t)M * 256);      // 4 per node

    // 1) CSR build (rank trick: no atomics in fill)
    hipMemsetAsync(counts, 0, (size_t)M * 4, stream);
    k_hist<<<(E + 255) / 256, 256, 0, stream>>>(dstp, counts, rank, E);
    k_psum<<<nscan, 256, 0, stream>>>(counts, part, M);
    k_scatter_rs<<<nscan, 256, 0, stream>>>(counts, part, row_start, M, E);
    k_fill<<<(E + 255) / 256, 256, 0, stream>>>(srcp, dstp, rank, row_start, csrc, E);

    // 2) conversions (single launch)
    int n4x = M * 128 / 4;
    int nbx = (n4x + 255) / 256;
    k_cvt_all<<<nbx + 128 + 256 + 256, 256, 0, stream>>>(
        (const float4*)x, (ushort4*)xb, n4x, nbx, W1, w1t, W2, w2t, W3, w3t);

    dim3 ggrid(4, (M + 255) / 256);
    int aggblocks = (M * 64 + 255) / 256;

    // layer 1: a1 = agg(x); h1 = quant8(relu(a1 @ W1 + b1))
    k_agg<<<aggblocks, 256, 0, stream>>>(xb, row_start, csrc, ab, M);
    k_gemm<true, 128><<<ggrid, 256, 0, stream>>>(ab, w1t, b1, h8, scales, M);

    // layer 2: a2 = agg8(h1); h2 = quant8(relu(a2 @ W2 + b2))
    k_agg8<<<aggblocks, 256, 0, stream>>>(h8, scales, row_start, csrc, ab, M);
    k_gemm<true, 256><<<ggrid, 256, 0, stream>>>(ab, w2t, b2, h8, scales, M);

    // layer 3: a3 = agg8(h2); out = relu(a3 @ W3 + b3)
    k_agg8<<<aggblocks, 256, 0, stream>>>(h8, scales, row_start, csrc, ab, M);
    k_gemm<false, 256><<<ggrid, 256, 0, stream>>>(ab, w3t, b3, d_out, nullptr, M);
}